// Round 1
// baseline (132.568 us; speedup 1.0000x reference)
//
#include <hip/hip_runtime.h>
#include <math.h>

// ---------------------------------------------------------------------------
// Problem: B=32, L=1024, C=34 (N=32 used channels), PATCH=16, p=64 patches,
// d=256, E=8 experts, pred=96.
// Key algebraic reductions (see analysis):
//   * final [:, :, :1] slice -> only channel n=0 per batch (series x[b,:,2])
//   * flat[:, :1024] truncation -> only patches p=0..3 contribute
// => 32 series, 4 patches each, 8 expert 256x256 matvecs per (b,p), one
//    96x1024 head matvec per b.  ~0.3 GFLOP total.
// ---------------------------------------------------------------------------

#define NB 32          // batches (= series we need)
#define LSEQ 1024
#define CCH 34
#define NP 4           // surviving patches
#define DMODEL 256
#define NEXP 8
#define PRED 96

// ws layout (floats):
//   [0, 524288)                      Wt  : transposed experts [e][d][h]
//   then xp_ws   : NB*NP*DMODEL = 32768
//   then gates_ws: NB*NP*NEXP   = 1024
//   then stats_ws: NB*2         = 64
//   then flat_ws : NB*1024      = 32768
#define WT_FLOATS   (NEXP * DMODEL * DMODEL)
#define XP_FLOATS   (NB * NP * DMODEL)
#define GATES_FLOATS (NB * NP * NEXP)
#define STATS_FLOATS (NB * 2)
#define FLAT_FLOATS (NB * LSEQ)

// ---------------------------------------------------------------------------
// Kernel A: per-batch stats, normalization, patch projection, router gates.
// Also zero-initializes flat_ws (ws is poisoned 0xAA before every launch).
// grid = 32, block = 256
// ---------------------------------------------------------------------------
__global__ __launch_bounds__(256) void k_stats(
    const float* __restrict__ x,
    const float* __restrict__ W_proj, const float* __restrict__ b_proj,
    const float* __restrict__ W_router, const float* __restrict__ b_router,
    float* __restrict__ xp_ws, float* __restrict__ gates_ws,
    float* __restrict__ stats_ws, float* __restrict__ flat_ws)
{
    const int b = blockIdx.x;
    const int tid = threadIdx.x;

    __shared__ float xn[LSEQ];
    __shared__ float xp_s[NP * DMODEL];
    __shared__ float red[8];
    __shared__ float lg[32];
    __shared__ float mean_s, rstd_s;

    // zero the flat accumulator row for this batch
    #pragma unroll
    for (int i = 0; i < 4; ++i)
        flat_ws[b * LSEQ + tid + 256 * i] = 0.0f;

    // load series x[b, l, 2] (stride 34 floats) and reduce sum/sumsq
    float v[4];
    float s = 0.f, sq = 0.f;
    #pragma unroll
    for (int i = 0; i < 4; ++i) {
        int l = tid + 256 * i;
        float val = x[(size_t)(b * LSEQ + l) * CCH + 2];
        v[i] = val;
        s += val;
        sq += val * val;
    }
    #pragma unroll
    for (int off = 32; off > 0; off >>= 1) {
        s  += __shfl_down(s,  off);
        sq += __shfl_down(sq, off);
    }
    const int wave = tid >> 6;
    if ((tid & 63) == 0) { red[wave * 2] = s; red[wave * 2 + 1] = sq; }
    __syncthreads();
    if (tid == 0) {
        float S = red[0] + red[2] + red[4] + red[6];
        float Q = red[1] + red[3] + red[5] + red[7];
        float mean = S * (1.0f / LSEQ);
        float var  = Q * (1.0f / LSEQ) - mean * mean;
        float stdv = sqrtf(var + 1e-5f);
        mean_s = mean;
        rstd_s = 1.0f / stdv;
        stats_ws[b * 2]     = mean;
        stats_ws[b * 2 + 1] = stdv;
    }
    __syncthreads();
    const float mean = mean_s, rstd = rstd_s;
    #pragma unroll
    for (int i = 0; i < 4; ++i)
        xn[tid + 256 * i] = (v[i] - mean) * rstd;
    __syncthreads();

    // xp[p][h] = b_proj[h] + sum_j xn[16p+j] * W_proj[h][j]   (thread h)
    {
        const int h = tid;
        float wrow[16];
        #pragma unroll
        for (int j = 0; j < 16; ++j) wrow[j] = W_proj[h * 16 + j];
        const float bp = b_proj[h];
        #pragma unroll
        for (int p = 0; p < NP; ++p) {
            float acc = bp;
            #pragma unroll
            for (int j = 0; j < 16; ++j) acc += xn[p * 16 + j] * wrow[j];
            xp_s[p * DMODEL + h] = acc;
            xp_ws[((size_t)b * NP + p) * DMODEL + h] = acc;
        }
    }
    __syncthreads();

    // router logits: threads 0..31, (p,e)
    if (tid < 32) {
        const int p = tid >> 3, e = tid & 7;
        float acc = b_router[e];
        const float* wr = W_router + e * DMODEL;
        const float* xp = xp_s + p * DMODEL;
        #pragma unroll 8
        for (int h = 0; h < DMODEL; ++h) acc += xp[h] * wr[h];
        lg[tid] = acc;
    }
    __syncthreads();

    // softmax over 8 experts: threads 0..3 (one per patch)
    if (tid < NP) {
        const int p = tid;
        float m = -1e30f;
        #pragma unroll
        for (int e = 0; e < NEXP; ++e) m = fmaxf(m, lg[p * 8 + e]);
        float ex[NEXP];
        float sum = 0.f;
        #pragma unroll
        for (int e = 0; e < NEXP; ++e) { ex[e] = expf(lg[p * 8 + e] - m); sum += ex[e]; }
        const float inv = 1.0f / sum;
        #pragma unroll
        for (int e = 0; e < NEXP; ++e)
            gates_ws[((size_t)b * NP + p) * NEXP + e] = ex[e] * inv;
    }
}

// ---------------------------------------------------------------------------
// Kernel B: transpose W_experts [e][h][d] -> Wt [e][d][h] (tiled, coalesced)
// grid = (8, 8, 8) = (e, h-tile, d-tile), block = (32, 8)
// ---------------------------------------------------------------------------
__global__ __launch_bounds__(256) void k_transpose(
    const float* __restrict__ W, float* __restrict__ Wt)
{
    __shared__ float tile[32][33];
    const int e  = blockIdx.x;
    const int h0 = blockIdx.y * 32;
    const int d0 = blockIdx.z * 32;
    const int tx = threadIdx.x, ty = threadIdx.y;
    const float* src = W  + ((size_t)e << 16);
    float*       dst = Wt + ((size_t)e << 16);
    #pragma unroll
    for (int i = 0; i < 4; ++i)
        tile[ty + 8 * i][tx] = src[(size_t)(h0 + ty + 8 * i) * DMODEL + d0 + tx];
    __syncthreads();
    #pragma unroll
    for (int i = 0; i < 4; ++i)
        dst[(size_t)(d0 + ty + 8 * i) * DMODEL + h0 + tx] = tile[tx][ty + 8 * i];
}

// ---------------------------------------------------------------------------
// Kernel C: expert matvecs + gate combine, accumulated into flat_ws.
// grid = 256: bid -> (b, h-quarter, e-half); block = 256: tid -> (p, h_local)
// Each wave has uniform p and 64 consecutive h -> Wt loads are 256B coalesced;
// the 4 p-waves read identical Wt addresses -> L1 temporal reuse.
// Two e-half blocks per output element combine via atomicAdd (commutative,
// deterministic).
// ---------------------------------------------------------------------------
__global__ __launch_bounds__(256) void k_expert(
    const float* __restrict__ Wt, const float* __restrict__ b_experts,
    const float* __restrict__ xp_ws, const float* __restrict__ gates_ws,
    float* __restrict__ flat_ws)
{
    const int bid = blockIdx.x;
    const int b  = bid >> 3;
    const int r  = bid & 7;
    const int hq = r >> 1;
    const int e0 = (r & 1) * 4;
    const int tid = threadIdx.x;
    const int p  = tid >> 6;
    const int hl = tid & 63;
    const int h  = hq * 64 + hl;

    __shared__ float xp_s[NP * DMODEL];
    __shared__ float g_s[NP * NEXP];

    #pragma unroll
    for (int i = 0; i < 4; ++i)
        xp_s[tid + 256 * i] = xp_ws[(size_t)b * (NP * DMODEL) + tid + 256 * i];
    if (tid < NP * NEXP) g_s[tid] = gates_ws[(size_t)b * (NP * NEXP) + tid];
    __syncthreads();

    const float* xp = xp_s + p * DMODEL;
    float acc = 0.0f;
    #pragma unroll 1
    for (int ei = 0; ei < 4; ++ei) {
        const int e = e0 + ei;
        const float* wt = Wt + ((size_t)e << 16) + h;
        float d0 = 0.f, d1 = 0.f, d2 = 0.f, d3 = 0.f;
        #pragma unroll 4
        for (int d = 0; d < DMODEL; d += 4) {
            d0 += wt[(size_t)(d + 0) << 8] * xp[d + 0];
            d1 += wt[(size_t)(d + 1) << 8] * xp[d + 1];
            d2 += wt[(size_t)(d + 2) << 8] * xp[d + 2];
            d3 += wt[(size_t)(d + 3) << 8] * xp[d + 3];
        }
        const float dot = (d0 + d1) + (d2 + d3);
        acc += g_s[p * NEXP + e] * (dot + b_experts[(e << 8) + h]);
    }
    atomicAdd(&flat_ws[(size_t)b * LSEQ + (p << 8) + h], acc);
}

// ---------------------------------------------------------------------------
// Kernel C' (fallback, no transpose buffer): direct W_experts[e][h][d] rows
// via float4 (uncoalesced across lanes but fully L2-resident).
// ---------------------------------------------------------------------------
__global__ __launch_bounds__(256) void k_expert_direct(
    const float* __restrict__ W, const float* __restrict__ b_experts,
    const float* __restrict__ xp_ws, const float* __restrict__ gates_ws,
    float* __restrict__ flat_ws)
{
    const int bid = blockIdx.x;
    const int b  = bid >> 3;
    const int r  = bid & 7;
    const int hq = r >> 1;
    const int e0 = (r & 1) * 4;
    const int tid = threadIdx.x;
    const int p  = tid >> 6;
    const int hl = tid & 63;
    const int h  = hq * 64 + hl;

    __shared__ float xp_s[NP * DMODEL];
    __shared__ float g_s[NP * NEXP];

    #pragma unroll
    for (int i = 0; i < 4; ++i)
        xp_s[tid + 256 * i] = xp_ws[(size_t)b * (NP * DMODEL) + tid + 256 * i];
    if (tid < NP * NEXP) g_s[tid] = gates_ws[(size_t)b * (NP * NEXP) + tid];
    __syncthreads();

    const float4* xp4 = (const float4*)(xp_s + p * DMODEL);
    float acc = 0.0f;
    #pragma unroll 1
    for (int ei = 0; ei < 4; ++ei) {
        const int e = e0 + ei;
        const float4* wrow = (const float4*)(W + (((size_t)e << 8) + h) * DMODEL);
        float d0 = 0.f, d1 = 0.f, d2 = 0.f, d3 = 0.f;
        #pragma unroll 4
        for (int d = 0; d < DMODEL / 4; d += 4) {
            float4 w0 = wrow[d + 0], x0 = xp4[d + 0];
            float4 w1 = wrow[d + 1], x1 = xp4[d + 1];
            float4 w2 = wrow[d + 2], x2 = xp4[d + 2];
            float4 w3 = wrow[d + 3], x3 = xp4[d + 3];
            d0 += w0.x * x0.x + w0.y * x0.y + w0.z * x0.z + w0.w * x0.w;
            d1 += w1.x * x1.x + w1.y * x1.y + w1.z * x1.z + w1.w * x1.w;
            d2 += w2.x * x2.x + w2.y * x2.y + w2.z * x2.z + w2.w * x2.w;
            d3 += w3.x * x3.x + w3.y * x3.y + w3.z * x3.z + w3.w * x3.w;
        }
        const float dot = (d0 + d1) + (d2 + d3);
        acc += g_s[p * NEXP + e] * (dot + b_experts[(e << 8) + h]);
    }
    atomicAdd(&flat_ws[(size_t)b * LSEQ + (p << 8) + h], acc);
}

// ---------------------------------------------------------------------------
// Kernel D: un-normalize + head matvec.  out[b,k] = b_head[k] +
//   sum_l (flat[b,l]*std[b]+mean[b]) * W_head[k,l]
// grid = 32, block = 128 (threads 0..95 compute the 96 outputs)
// ---------------------------------------------------------------------------
__global__ __launch_bounds__(128) void k_head(
    const float* __restrict__ flat_ws, const float* __restrict__ stats_ws,
    const float* __restrict__ W_head, const float* __restrict__ b_head,
    float* __restrict__ out)
{
    const int b = blockIdx.x;
    const int tid = threadIdx.x;
    __shared__ float f_s[LSEQ];

    const float mean = stats_ws[b * 2];
    const float stdv = stats_ws[b * 2 + 1];
    #pragma unroll
    for (int i = 0; i < 8; ++i) {
        const int idx = tid + 128 * i;
        f_s[idx] = flat_ws[(size_t)b * LSEQ + idx] * stdv + mean;
    }
    __syncthreads();

    if (tid < PRED) {
        const float4* wr = (const float4*)(W_head + (size_t)tid * LSEQ);
        const float4* f4 = (const float4*)f_s;
        float a0 = 0.f, a1 = 0.f, a2 = 0.f, a3 = 0.f;
        #pragma unroll 4
        for (int i = 0; i < LSEQ / 4; i += 4) {
            float4 w0 = wr[i + 0], x0 = f4[i + 0];
            float4 w1 = wr[i + 1], x1 = f4[i + 1];
            float4 w2 = wr[i + 2], x2 = f4[i + 2];
            float4 w3 = wr[i + 3], x3 = f4[i + 3];
            a0 += w0.x * x0.x + w0.y * x0.y + w0.z * x0.z + w0.w * x0.w;
            a1 += w1.x * x1.x + w1.y * x1.y + w1.z * x1.z + w1.w * x1.w;
            a2 += w2.x * x2.x + w2.y * x2.y + w2.z * x2.z + w2.w * x2.w;
            a3 += w3.x * x3.x + w3.y * x3.y + w3.z * x3.z + w3.w * x3.w;
        }
        out[(size_t)b * PRED + tid] = b_head[tid] + (a0 + a1) + (a2 + a3);
    }
}

// ---------------------------------------------------------------------------
extern "C" void kernel_launch(void* const* d_in, const int* in_sizes, int n_in,
                              void* d_out, int out_size, void* d_ws, size_t ws_size,
                              hipStream_t stream)
{
    const float* x         = (const float*)d_in[0];
    const float* W_proj    = (const float*)d_in[4];
    const float* b_proj    = (const float*)d_in[5];
    const float* W_router  = (const float*)d_in[6];
    const float* b_router  = (const float*)d_in[7];
    const float* W_experts = (const float*)d_in[8];
    const float* b_experts = (const float*)d_in[9];
    const float* W_head    = (const float*)d_in[10];
    const float* b_head    = (const float*)d_in[11];
    float* out = (float*)d_out;
    float* ws  = (float*)d_ws;

    const size_t small_floats = XP_FLOATS + GATES_FLOATS + STATS_FLOATS + FLAT_FLOATS;
    const bool use_t = ws_size >= (WT_FLOATS + small_floats) * sizeof(float);

    size_t off = use_t ? (size_t)WT_FLOATS : 0;
    float* Wt       = ws;
    float* xp_ws    = ws + off;            off += XP_FLOATS;
    float* gates_ws = ws + off;            off += GATES_FLOATS;
    float* stats_ws = ws + off;            off += STATS_FLOATS;
    float* flat_ws  = ws + off;

    k_stats<<<NB, 256, 0, stream>>>(x, W_proj, b_proj, W_router, b_router,
                                    xp_ws, gates_ws, stats_ws, flat_ws);
    if (use_t) {
        k_transpose<<<dim3(8, 8, 8), dim3(32, 8), 0, stream>>>(W_experts, Wt);
        k_expert<<<256, 256, 0, stream>>>(Wt, b_experts, xp_ws, gates_ws, flat_ws);
    } else {
        k_expert_direct<<<256, 256, 0, stream>>>(W_experts, b_experts,
                                                 xp_ws, gates_ws, flat_ws);
    }
    k_head<<<NB, 128, 0, stream>>>(flat_ws, stats_ws, W_head, b_head, out);
}

// Round 2
// 118.187 us; speedup vs baseline: 1.1217x; 1.1217x over previous
//
#include <hip/hip_runtime.h>
#include <math.h>

// ---------------------------------------------------------------------------
// Problem: B=32, L=1024, C=34, PATCH=16, d=256, E=8, pred=96.
// Algebraic reductions (verified passing in R1):
//   * final [:, :, :1] slice -> only channel n=0 per batch (series x[b,:,2])
//   * flat[:, :1024] truncation -> only patches p=0..3 contribute
// => 32 series, 4 patches each, 8 expert 256x256 matvecs per (b,p), one
//    96x1024 head matvec per b.  ~0.3 GFLOP total; latency-bound.
//
// R2 structure (3 kernels, no atomics):
//   k_stats : per-batch stats/norm/proj/router  + fused W_experts transpose
//   k_expert: 1024 blocks (b x h-quarter x expert), coalesced Wt loads,
//             writes disjoint per-expert partial buffers (no init needed)
//   k_head  : sums 8 partials while staging, un-normalizes, 96x1024 matvec
// ---------------------------------------------------------------------------

#define NB 32
#define LSEQ 1024
#define CCH 34
#define NP 4
#define DMODEL 256
#define NEXP 8
#define PRED 96

#define WT_FLOATS    (NEXP * DMODEL * DMODEL)   // 524288
#define XP_FLOATS    (NB * NP * DMODEL)         // 32768
#define GATES_FLOATS (NB * NP * NEXP)           // 1024
#define STATS_FLOATS (NB * 2)                   // 64
#define FLAT_FLOATS  (NEXP * NB * LSEQ)         // 262144 (8 partial buffers)

// ---------------------------------------------------------------------------
// Kernel A: fused transpose slice + stats + normalize + patch proj + router.
// grid = 32, block = 256.  Block b transposes W_experts[e=b>>2][h0..h0+64][:]
// into Wt[e][:][h0..h0+64] (LDS tile, conflict-free), overlapping the
// long-latency strided x loads issued first.
// ---------------------------------------------------------------------------
__global__ __launch_bounds__(256) void k_stats(
    const float* __restrict__ x,
    const float* __restrict__ W_proj, const float* __restrict__ b_proj,
    const float* __restrict__ W_router, const float* __restrict__ b_router,
    const float* __restrict__ W_experts, float* __restrict__ Wt,
    float* __restrict__ xp_ws, float* __restrict__ gates_ws,
    float* __restrict__ stats_ws)
{
    const int b = blockIdx.x;
    const int tid = threadIdx.x;

    __shared__ float tile[64][33];
    __shared__ float xn[LSEQ];
    __shared__ float xp_s[NP * DMODEL];
    __shared__ float red[8];
    __shared__ float lg[32];
    __shared__ float mean_s, rstd_s;

    // issue the strided series loads FIRST (long HBM latency, consumed later)
    float v[4];
    #pragma unroll
    for (int i = 0; i < 4; ++i)
        v[i] = x[(size_t)(b * LSEQ + tid + 256 * i) * CCH + 2];

    // ---- fused transpose: W[e][h0+0..64][0..256] -> Wt[e][0..256][h0+0..64]
    {
        const int e  = b >> 2;
        const int h0 = (b & 3) * 64;
        const float* src = W_experts + ((size_t)e << 16);
        float*       dst = Wt        + ((size_t)e << 16);
        const int dx  = tid & 31, hy = tid >> 5;   // load: 32 d-lanes x 8 h-rows
        const int hx  = tid & 63, dy = tid >> 6;   // store: 64 h-lanes x 4 d-rows
        for (int d0 = 0; d0 < DMODEL; d0 += 32) {
            #pragma unroll
            for (int i = 0; i < 8; ++i) {
                const int hh = hy + 8 * i;
                tile[hh][dx] = src[(size_t)(h0 + hh) * DMODEL + d0 + dx];
            }
            __syncthreads();
            #pragma unroll
            for (int i = 0; i < 8; ++i) {
                const int dd = dy + 4 * i;
                dst[(size_t)(d0 + dd) * DMODEL + h0 + hx] = tile[hx][dd];
            }
            __syncthreads();
        }
    }

    // ---- stats over the 1024-length series
    float s = 0.f, sq = 0.f;
    #pragma unroll
    for (int i = 0; i < 4; ++i) { s += v[i]; sq += v[i] * v[i]; }
    #pragma unroll
    for (int off = 32; off > 0; off >>= 1) {
        s  += __shfl_down(s,  off);
        sq += __shfl_down(sq, off);
    }
    const int wave = tid >> 6;
    if ((tid & 63) == 0) { red[wave * 2] = s; red[wave * 2 + 1] = sq; }
    __syncthreads();
    if (tid == 0) {
        const float S = red[0] + red[2] + red[4] + red[6];
        const float Q = red[1] + red[3] + red[5] + red[7];
        const float mean = S * (1.0f / LSEQ);
        const float var  = Q * (1.0f / LSEQ) - mean * mean;
        const float stdv = sqrtf(var + 1e-5f);
        mean_s = mean;
        rstd_s = 1.0f / stdv;
        stats_ws[b * 2]     = mean;
        stats_ws[b * 2 + 1] = stdv;
    }
    __syncthreads();
    const float mean = mean_s, rstd = rstd_s;
    #pragma unroll
    for (int i = 0; i < 4; ++i)
        xn[tid + 256 * i] = (v[i] - mean) * rstd;
    __syncthreads();

    // ---- patch projection: xp[p][h], thread h
    {
        const int h = tid;
        float wrow[16];
        #pragma unroll
        for (int j = 0; j < 16; ++j) wrow[j] = W_proj[h * 16 + j];
        const float bp = b_proj[h];
        #pragma unroll
        for (int p = 0; p < NP; ++p) {
            float acc = bp;
            #pragma unroll
            for (int j = 0; j < 16; ++j) acc += xn[p * 16 + j] * wrow[j];
            xp_s[p * DMODEL + h] = acc;
            xp_ws[((size_t)b * NP + p) * DMODEL + h] = acc;
        }
    }
    __syncthreads();

    // ---- router logits (threads 0..31 -> (p,e))
    if (tid < 32) {
        const int p = tid >> 3, e = tid & 7;
        float acc = b_router[e];
        const float* wr = W_router + e * DMODEL;
        const float* xp = xp_s + p * DMODEL;
        #pragma unroll 8
        for (int h = 0; h < DMODEL; ++h) acc += xp[h] * wr[h];
        lg[tid] = acc;
    }
    __syncthreads();

    // ---- softmax over 8 experts (threads 0..3 -> p)
    if (tid < NP) {
        const int p = tid;
        float m = -1e30f;
        #pragma unroll
        for (int e = 0; e < NEXP; ++e) m = fmaxf(m, lg[p * 8 + e]);
        float ex[NEXP];
        float sum = 0.f;
        #pragma unroll
        for (int e = 0; e < NEXP; ++e) { ex[e] = expf(lg[p * 8 + e] - m); sum += ex[e]; }
        const float inv = 1.0f / sum;
        #pragma unroll
        for (int e = 0; e < NEXP; ++e)
            gates_ws[((size_t)b * NP + p) * NEXP + e] = ex[e] * inv;
    }
}

// ---------------------------------------------------------------------------
// Kernel B: expert matvecs, gate-weighted, written to per-expert partials.
// grid = 1024: bid -> (b, hq, e); block = 256: tid -> (p, h_local).
// Wt loads are 256B lane-coalesced; the 4 p-waves read identical addresses
// (L1 temporal reuse).  No atomics: flat_part[e] buffers are disjoint.
// ---------------------------------------------------------------------------
__global__ __launch_bounds__(256) void k_expert(
    const float* __restrict__ Wt, const float* __restrict__ b_experts,
    const float* __restrict__ xp_ws, const float* __restrict__ gates_ws,
    float* __restrict__ flat_part)
{
    const int bid = blockIdx.x;
    const int b  = bid >> 5;
    const int r  = bid & 31;
    const int hq = r >> 3;
    const int e  = r & 7;
    const int tid = threadIdx.x;
    const int p  = tid >> 6;
    const int hl = tid & 63;
    const int h  = (hq << 6) + hl;

    __shared__ float xp_s[NP * DMODEL];
    __shared__ float g_s[NP * NEXP];

    #pragma unroll
    for (int i = 0; i < 4; ++i)
        xp_s[tid + 256 * i] = xp_ws[(size_t)b * (NP * DMODEL) + tid + 256 * i];
    if (tid < NP * NEXP) g_s[tid] = gates_ws[(size_t)b * (NP * NEXP) + tid];
    __syncthreads();

    const float* xp = xp_s + (p << 8);
    const float* wt = Wt + ((size_t)e << 16) + h;
    const float bias = b_experts[(e << 8) + h];
    const float gate = g_s[(p << 3) + e];

    float d0 = 0.f, d1 = 0.f, d2 = 0.f, d3 = 0.f;
    #pragma unroll 4
    for (int d = 0; d < DMODEL; d += 4) {
        d0 += wt[(size_t)(d + 0) << 8] * xp[d + 0];
        d1 += wt[(size_t)(d + 1) << 8] * xp[d + 1];
        d2 += wt[(size_t)(d + 2) << 8] * xp[d + 2];
        d3 += wt[(size_t)(d + 3) << 8] * xp[d + 3];
    }
    const float dot = (d0 + d1) + (d2 + d3);
    flat_part[(((size_t)e * NB + b) << 10) + (p << 8) + h] = gate * (dot + bias);
}

// ---------------------------------------------------------------------------
// Kernel B' fallback (no Wt buffer): direct W rows, per-lane float4.
// ---------------------------------------------------------------------------
__global__ __launch_bounds__(256) void k_expert_direct(
    const float* __restrict__ W, const float* __restrict__ b_experts,
    const float* __restrict__ xp_ws, const float* __restrict__ gates_ws,
    float* __restrict__ flat_part)
{
    const int bid = blockIdx.x;
    const int b  = bid >> 5;
    const int r  = bid & 31;
    const int hq = r >> 3;
    const int e  = r & 7;
    const int tid = threadIdx.x;
    const int p  = tid >> 6;
    const int hl = tid & 63;
    const int h  = (hq << 6) + hl;

    __shared__ float xp_s[NP * DMODEL];
    __shared__ float g_s[NP * NEXP];

    #pragma unroll
    for (int i = 0; i < 4; ++i)
        xp_s[tid + 256 * i] = xp_ws[(size_t)b * (NP * DMODEL) + tid + 256 * i];
    if (tid < NP * NEXP) g_s[tid] = gates_ws[(size_t)b * (NP * NEXP) + tid];
    __syncthreads();

    const float4* xp4 = (const float4*)(xp_s + (p << 8));
    const float4* wrow = (const float4*)(W + (((size_t)e << 8) + h) * DMODEL);
    const float bias = b_experts[(e << 8) + h];
    const float gate = g_s[(p << 3) + e];

    float d0 = 0.f, d1 = 0.f, d2 = 0.f, d3 = 0.f;
    #pragma unroll 4
    for (int d = 0; d < DMODEL / 4; d += 4) {
        float4 w0 = wrow[d + 0], x0 = xp4[d + 0];
        float4 w1 = wrow[d + 1], x1 = xp4[d + 1];
        float4 w2 = wrow[d + 2], x2 = xp4[d + 2];
        float4 w3 = wrow[d + 3], x3 = xp4[d + 3];
        d0 += w0.x * x0.x + w0.y * x0.y + w0.z * x0.z + w0.w * x0.w;
        d1 += w1.x * x1.x + w1.y * x1.y + w1.z * x1.z + w1.w * x1.w;
        d2 += w2.x * x2.x + w2.y * x2.y + w2.z * x2.z + w2.w * x2.w;
        d3 += w3.x * x3.x + w3.y * x3.y + w3.z * x3.z + w3.w * x3.w;
    }
    const float dot = (d0 + d1) + (d2 + d3);
    flat_part[(((size_t)e * NB + b) << 10) + (p << 8) + h] = gate * (dot + bias);
}

// ---------------------------------------------------------------------------
// Kernel C: sum 8 partials, un-normalize, head matvec.
// grid = 32, block = 128 (threads 0..95 produce the 96 outputs).
// ---------------------------------------------------------------------------
__global__ __launch_bounds__(128) void k_head(
    const float* __restrict__ flat_part, const float* __restrict__ stats_ws,
    const float* __restrict__ W_head, const float* __restrict__ b_head,
    float* __restrict__ out)
{
    const int b = blockIdx.x;
    const int tid = threadIdx.x;
    __shared__ float f_s[LSEQ];

    const float mean = stats_ws[b * 2];
    const float stdv = stats_ws[b * 2 + 1];

    // stage: f[l] = (sum_e part[e][b][l]) * std + mean   (float4, coalesced)
    float4* f4s = (float4*)f_s;
    #pragma unroll
    for (int i = 0; i < 2; ++i) {
        const int idx = tid + 128 * i;           // float4 index within 256
        float4 acc = make_float4(0.f, 0.f, 0.f, 0.f);
        #pragma unroll
        for (int e = 0; e < NEXP; ++e) {
            const float4 t = ((const float4*)(flat_part + (((size_t)e * NB + b) << 10)))[idx];
            acc.x += t.x; acc.y += t.y; acc.z += t.z; acc.w += t.w;
        }
        acc.x = acc.x * stdv + mean;
        acc.y = acc.y * stdv + mean;
        acc.z = acc.z * stdv + mean;
        acc.w = acc.w * stdv + mean;
        f4s[idx] = acc;
    }
    __syncthreads();

    if (tid < PRED) {
        const float4* wr = (const float4*)(W_head + (size_t)tid * LSEQ);
        const float4* f4 = (const float4*)f_s;
        float a0 = 0.f, a1 = 0.f, a2 = 0.f, a3 = 0.f;
        #pragma unroll 4
        for (int i = 0; i < LSEQ / 4; i += 4) {
            float4 w0 = wr[i + 0], x0 = f4[i + 0];
            float4 w1 = wr[i + 1], x1 = f4[i + 1];
            float4 w2 = wr[i + 2], x2 = f4[i + 2];
            float4 w3 = wr[i + 3], x3 = f4[i + 3];
            a0 += w0.x * x0.x + w0.y * x0.y + w0.z * x0.z + w0.w * x0.w;
            a1 += w1.x * x1.x + w1.y * x1.y + w1.z * x1.z + w1.w * x1.w;
            a2 += w2.x * x2.x + w2.y * x2.y + w2.z * x2.z + w2.w * x2.w;
            a3 += w3.x * x3.x + w3.y * x3.y + w3.z * x3.z + w3.w * x3.w;
        }
        out[(size_t)b * PRED + tid] = b_head[tid] + (a0 + a1) + (a2 + a3);
    }
}

// ---------------------------------------------------------------------------
extern "C" void kernel_launch(void* const* d_in, const int* in_sizes, int n_in,
                              void* d_out, int out_size, void* d_ws, size_t ws_size,
                              hipStream_t stream)
{
    const float* x         = (const float*)d_in[0];
    const float* W_proj    = (const float*)d_in[4];
    const float* b_proj    = (const float*)d_in[5];
    const float* W_router  = (const float*)d_in[6];
    const float* b_router  = (const float*)d_in[7];
    const float* W_experts = (const float*)d_in[8];
    const float* b_experts = (const float*)d_in[9];
    const float* W_head    = (const float*)d_in[10];
    const float* b_head    = (const float*)d_in[11];
    float* out = (float*)d_out;
    float* ws  = (float*)d_ws;

    const size_t need = (size_t)(WT_FLOATS + XP_FLOATS + GATES_FLOATS +
                                 STATS_FLOATS + FLAT_FLOATS);
    const bool use_t = ws_size >= need * sizeof(float);

    size_t off = use_t ? (size_t)WT_FLOATS : 0;
    float* Wt        = ws;
    float* xp_ws     = ws + off;  off += XP_FLOATS;
    float* gates_ws  = ws + off;  off += GATES_FLOATS;
    float* stats_ws  = ws + off;  off += STATS_FLOATS;
    float* flat_part = ws + off;

    if (use_t) {
        k_stats<<<NB, 256, 0, stream>>>(x, W_proj, b_proj, W_router, b_router,
                                        W_experts, Wt, xp_ws, gates_ws, stats_ws);
        k_expert<<<1024, 256, 0, stream>>>(Wt, b_experts, xp_ws, gates_ws, flat_part);
    } else {
        // fallback: no transpose buffer -> still need stats/xp/gates; reuse
        // k_stats with Wt pointing at xp_ws-adjacent scratch is unsafe, so
        // run k_stats with a dummy Wt region only if space permits; here we
        // simply run the transpose-free path writing Wt into the same region
        // (never taken with the observed 256 MiB workspace).
        k_stats<<<NB, 256, 0, stream>>>(x, W_proj, b_proj, W_router, b_router,
                                        W_experts, ws, xp_ws, gates_ws, stats_ws);
        k_expert_direct<<<1024, 256, 0, stream>>>(W_experts, b_experts,
                                                  xp_ws, gates_ws, flat_part);
    }
    k_head<<<NB, 128, 0, stream>>>(flat_part, stats_ws, W_head, b_head, out);
}

// Round 3
// 114.512 us; speedup vs baseline: 1.1577x; 1.0321x over previous
//
#include <hip/hip_runtime.h>
#include <math.h>

// ---------------------------------------------------------------------------
// Problem: B=32, L=1024, C=34, PATCH=16, d=256, E=8, pred=96.
// Algebraic reductions (verified passing R1/R2):
//   * final [:, :, :1] slice -> only channel n=0 per batch (series x[b,:,2])
//   * flat[:, :1024] truncation -> only patches p=0..3 contribute
// => 32 series, 4 patches each, 8 expert 256x256 matvecs per (b,p), one
//    96x1024 head matvec per b.  ~0.3 GFLOP; latency/launch-bound.
//
// R3 structure (3 kernels):
//   k_stats : 256 blocks. ALL blocks transpose one 64x32 tile of W_experts
//             (8x wider than R2's 32-block transpose); blocks 0-31 also do
//             stats/norm/proj/router for batch b.
//   k_expert: 1024 blocks (b x h-quarter x expert), coalesced Wt columns,
//             disjoint per-expert partial outputs (no atomics, no init).
//   k_head  : 32 blocks x 256 thr; stage f in LDS once, registers per lane,
//             wave-per-k coalesced W_head loads + shfl_xor butterfly.
// ---------------------------------------------------------------------------

#define NB 32
#define LSEQ 1024
#define CCH 34
#define NP 4
#define DMODEL 256
#define NEXP 8
#define PRED 96

#define WT_FLOATS    (NEXP * DMODEL * DMODEL)   // 524288
#define XP_FLOATS    (NB * NP * DMODEL)         // 32768
#define GATES_FLOATS (NB * NP * NEXP)           // 1024
#define STATS_FLOATS (NB * 2)                   // 64
#define FLAT_FLOATS  (NEXP * NB * LSEQ)         // 262144 (8 partial buffers)

// ---------------------------------------------------------------------------
// Kernel A: distributed transpose + (blocks 0-31) stats/norm/proj/router.
// grid = 256, block = 256.
// Transpose decomposition: bid -> (e = bid>>5, h-tile = (bid>>3)&3 (64 wide),
// d-tile = bid&7 (32 wide)).  LDS tile [64][33] -> conflict-free both ways.
// ---------------------------------------------------------------------------
__global__ __launch_bounds__(256) void k_stats(
    const float* __restrict__ x,
    const float* __restrict__ W_proj, const float* __restrict__ b_proj,
    const float* __restrict__ W_router, const float* __restrict__ b_router,
    const float* __restrict__ W_experts, float* __restrict__ Wt,
    float* __restrict__ xp_ws, float* __restrict__ gates_ws,
    float* __restrict__ stats_ws, int do_transpose)
{
    const int bid = blockIdx.x;
    const int tid = threadIdx.x;
    const int b = bid;            // batch id, valid only for bid < NB

    __shared__ float tile[64][33];
    __shared__ float xn[LSEQ];
    __shared__ float xp_s[NP * DMODEL];
    __shared__ float red[8];
    __shared__ float lg[32];
    __shared__ float mean_s, rstd_s;

    // stats blocks: issue the strided series loads FIRST (long HBM latency,
    // consumed after the transpose work below)
    float v[4];
    if (b < NB) {
        #pragma unroll
        for (int i = 0; i < 4; ++i)
            v[i] = x[(size_t)(b * LSEQ + tid + 256 * i) * CCH + 2];
    }

    // ---- distributed transpose: one 64(h) x 32(d) tile per block
    if (do_transpose) {
        const int e  = bid >> 5;
        const int h0 = ((bid >> 3) & 3) << 6;
        const int d0 = (bid & 7) << 5;
        const float* src = W_experts + ((size_t)e << 16);
        float*       dst = Wt        + ((size_t)e << 16);
        const int dx = tid & 31, hy = tid >> 5;   // load: 32 d-lanes x 8 h-rows
        const int hx = tid & 63, dy = tid >> 6;   // store: 64 h-lanes x 4 d-rows
        #pragma unroll
        for (int i = 0; i < 8; ++i) {
            const int hh = hy + 8 * i;
            tile[hh][dx] = src[(size_t)(h0 + hh) * DMODEL + d0 + dx];
        }
        __syncthreads();
        #pragma unroll
        for (int i = 0; i < 8; ++i) {
            const int dd = dy + 4 * i;
            dst[(size_t)(d0 + dd) * DMODEL + h0 + hx] = tile[hx][dd];
        }
    }

    if (b >= NB) return;   // transpose-only blocks done

    // ---- stats over the 1024-length series
    float s = 0.f, sq = 0.f;
    #pragma unroll
    for (int i = 0; i < 4; ++i) { s += v[i]; sq += v[i] * v[i]; }
    #pragma unroll
    for (int off = 32; off > 0; off >>= 1) {
        s  += __shfl_down(s,  off);
        sq += __shfl_down(sq, off);
    }
    const int wave = tid >> 6;
    if ((tid & 63) == 0) { red[wave * 2] = s; red[wave * 2 + 1] = sq; }
    __syncthreads();
    if (tid == 0) {
        const float S = red[0] + red[2] + red[4] + red[6];
        const float Q = red[1] + red[3] + red[5] + red[7];
        const float mean = S * (1.0f / LSEQ);
        const float var  = Q * (1.0f / LSEQ) - mean * mean;
        const float stdv = sqrtf(var + 1e-5f);
        mean_s = mean;
        rstd_s = 1.0f / stdv;
        stats_ws[b * 2]     = mean;
        stats_ws[b * 2 + 1] = stdv;
    }
    __syncthreads();
    const float mean = mean_s, rstd = rstd_s;
    #pragma unroll
    for (int i = 0; i < 4; ++i)
        xn[tid + 256 * i] = (v[i] - mean) * rstd;
    __syncthreads();

    // ---- patch projection: xp[p][h], thread h
    {
        const int h = tid;
        float wrow[16];
        #pragma unroll
        for (int j = 0; j < 16; ++j) wrow[j] = W_proj[h * 16 + j];
        const float bp = b_proj[h];
        #pragma unroll
        for (int p = 0; p < NP; ++p) {
            float acc = bp;
            #pragma unroll
            for (int j = 0; j < 16; ++j) acc += xn[p * 16 + j] * wrow[j];
            xp_s[p * DMODEL + h] = acc;
            xp_ws[((size_t)b * NP + p) * DMODEL + h] = acc;
        }
    }
    __syncthreads();

    // ---- router logits (threads 0..31 -> (p,e))
    if (tid < 32) {
        const int p = tid >> 3, e = tid & 7;
        float acc = b_router[e];
        const float* wr = W_router + e * DMODEL;
        const float* xp = xp_s + p * DMODEL;
        #pragma unroll 8
        for (int h = 0; h < DMODEL; ++h) acc += xp[h] * wr[h];
        lg[tid] = acc;
    }
    __syncthreads();

    // ---- softmax over 8 experts (threads 0..3 -> p)
    if (tid < NP) {
        const int p = tid;
        float m = -1e30f;
        #pragma unroll
        for (int e = 0; e < NEXP; ++e) m = fmaxf(m, lg[p * 8 + e]);
        float ex[NEXP];
        float sum = 0.f;
        #pragma unroll
        for (int e = 0; e < NEXP; ++e) { ex[e] = expf(lg[p * 8 + e] - m); sum += ex[e]; }
        const float inv = 1.0f / sum;
        #pragma unroll
        for (int e = 0; e < NEXP; ++e)
            gates_ws[((size_t)b * NP + p) * NEXP + e] = ex[e] * inv;
    }
}

// ---------------------------------------------------------------------------
// Kernel B: expert matvecs, gate-weighted, written to per-expert partials.
// grid = 1024: bid -> (b, hq, e); block = 256: tid -> (p, h_local).
// Wt loads are 256B lane-coalesced; the 4 p-waves read identical addresses
// (L1 temporal reuse).  No atomics: flat_part[e] buffers are disjoint.
// ---------------------------------------------------------------------------
__global__ __launch_bounds__(256) void k_expert(
    const float* __restrict__ Wt, const float* __restrict__ b_experts,
    const float* __restrict__ xp_ws, const float* __restrict__ gates_ws,
    float* __restrict__ flat_part)
{
    const int bid = blockIdx.x;
    const int b  = bid >> 5;
    const int r  = bid & 31;
    const int hq = r >> 3;
    const int e  = r & 7;
    const int tid = threadIdx.x;
    const int p  = tid >> 6;
    const int hl = tid & 63;
    const int h  = (hq << 6) + hl;

    __shared__ float xp_s[NP * DMODEL];
    __shared__ float g_s[NP * NEXP];

    #pragma unroll
    for (int i = 0; i < 4; ++i)
        xp_s[tid + 256 * i] = xp_ws[(size_t)b * (NP * DMODEL) + tid + 256 * i];
    if (tid < NP * NEXP) g_s[tid] = gates_ws[(size_t)b * (NP * NEXP) + tid];
    __syncthreads();

    const float* xp = xp_s + (p << 8);
    const float* wt = Wt + ((size_t)e << 16) + h;
    const float bias = b_experts[(e << 8) + h];
    const float gate = g_s[(p << 3) + e];

    float d0 = 0.f, d1 = 0.f, d2 = 0.f, d3 = 0.f;
    #pragma unroll 4
    for (int d = 0; d < DMODEL; d += 4) {
        d0 += wt[(size_t)(d + 0) << 8] * xp[d + 0];
        d1 += wt[(size_t)(d + 1) << 8] * xp[d + 1];
        d2 += wt[(size_t)(d + 2) << 8] * xp[d + 2];
        d3 += wt[(size_t)(d + 3) << 8] * xp[d + 3];
    }
    const float dot = (d0 + d1) + (d2 + d3);
    flat_part[(((size_t)e * NB + b) << 10) + (p << 8) + h] = gate * (dot + bias);
}

// ---------------------------------------------------------------------------
// Kernel B' fallback (no Wt buffer): direct W rows, per-lane float4.
// ---------------------------------------------------------------------------
__global__ __launch_bounds__(256) void k_expert_direct(
    const float* __restrict__ W, const float* __restrict__ b_experts,
    const float* __restrict__ xp_ws, const float* __restrict__ gates_ws,
    float* __restrict__ flat_part)
{
    const int bid = blockIdx.x;
    const int b  = bid >> 5;
    const int r  = bid & 31;
    const int hq = r >> 3;
    const int e  = r & 7;
    const int tid = threadIdx.x;
    const int p  = tid >> 6;
    const int hl = tid & 63;
    const int h  = (hq << 6) + hl;

    __shared__ float xp_s[NP * DMODEL];
    __shared__ float g_s[NP * NEXP];

    #pragma unroll
    for (int i = 0; i < 4; ++i)
        xp_s[tid + 256 * i] = xp_ws[(size_t)b * (NP * DMODEL) + tid + 256 * i];
    if (tid < NP * NEXP) g_s[tid] = gates_ws[(size_t)b * (NP * NEXP) + tid];
    __syncthreads();

    const float4* xp4 = (const float4*)(xp_s + (p << 8));
    const float4* wrow = (const float4*)(W + (((size_t)e << 8) + h) * DMODEL);
    const float bias = b_experts[(e << 8) + h];
    const float gate = g_s[(p << 3) + e];

    float d0 = 0.f, d1 = 0.f, d2 = 0.f, d3 = 0.f;
    #pragma unroll 4
    for (int d = 0; d < DMODEL / 4; d += 4) {
        float4 w0 = wrow[d + 0], x0 = xp4[d + 0];
        float4 w1 = wrow[d + 1], x1 = xp4[d + 1];
        float4 w2 = wrow[d + 2], x2 = xp4[d + 2];
        float4 w3 = wrow[d + 3], x3 = xp4[d + 3];
        d0 += w0.x * x0.x + w0.y * x0.y + w0.z * x0.z + w0.w * x0.w;
        d1 += w1.x * x1.x + w1.y * x1.y + w1.z * x1.z + w1.w * x1.w;
        d2 += w2.x * x2.x + w2.y * x2.y + w2.z * x2.z + w2.w * x2.w;
        d3 += w3.x * x3.x + w3.y * x3.y + w3.z * x3.z + w3.w * x3.w;
    }
    const float dot = (d0 + d1) + (d2 + d3);
    flat_part[(((size_t)e * NB + b) << 10) + (p << 8) + h] = gate * (dot + bias);
}

// ---------------------------------------------------------------------------
// Kernel C: sum 8 partials, un-normalize, head matvec.
// grid = 32, block = 256 (4 waves).  Stage f in LDS once, then registers;
// wave w computes k = w + 4*i (i < 24): W_head row loads are lane-coalesced
// (64 lanes x 16B = 1KB/instr), dot reduced with a 6-step shfl_xor butterfly.
// ---------------------------------------------------------------------------
__global__ __launch_bounds__(256) void k_head(
    const float* __restrict__ flat_part, const float* __restrict__ stats_ws,
    const float* __restrict__ W_head, const float* __restrict__ b_head,
    float* __restrict__ out)
{
    const int b = blockIdx.x;
    const int tid = threadIdx.x;
    __shared__ float4 f4s[DMODEL];   // 1024 floats

    const float mean = stats_ws[b * 2];
    const float stdv = stats_ws[b * 2 + 1];

    // stage: f[l] = (sum_e part[e][b][l]) * std + mean   (one float4/thread)
    {
        float4 acc = make_float4(0.f, 0.f, 0.f, 0.f);
        #pragma unroll
        for (int e = 0; e < NEXP; ++e) {
            const float4 t = ((const float4*)(flat_part + (((size_t)e * NB + b) << 10)))[tid];
            acc.x += t.x; acc.y += t.y; acc.z += t.z; acc.w += t.w;
        }
        acc.x = acc.x * stdv + mean;
        acc.y = acc.y * stdv + mean;
        acc.z = acc.z * stdv + mean;
        acc.w = acc.w * stdv + mean;
        f4s[tid] = acc;
    }
    __syncthreads();

    const int lane = tid & 63;
    const int w    = tid >> 6;

    // registers: lane holds f chunks lane+64c (16 floats)
    float4 fr[4];
    #pragma unroll
    for (int c = 0; c < 4; ++c) fr[c] = f4s[lane + 64 * c];

    #pragma unroll 2
    for (int i = 0; i < PRED / 4; ++i) {
        const int k = w + 4 * i;
        const float4* wr = (const float4*)(W_head + (size_t)k * LSEQ);
        float a = 0.f;
        #pragma unroll
        for (int c = 0; c < 4; ++c) {
            const float4 t = wr[lane + 64 * c];
            a += t.x * fr[c].x + t.y * fr[c].y + t.z * fr[c].z + t.w * fr[c].w;
        }
        #pragma unroll
        for (int off = 32; off > 0; off >>= 1)
            a += __shfl_xor(a, off);
        if (lane == 0)
            out[(size_t)b * PRED + k] = b_head[k] + a;
    }
}

// ---------------------------------------------------------------------------
extern "C" void kernel_launch(void* const* d_in, const int* in_sizes, int n_in,
                              void* d_out, int out_size, void* d_ws, size_t ws_size,
                              hipStream_t stream)
{
    const float* x         = (const float*)d_in[0];
    const float* W_proj    = (const float*)d_in[4];
    const float* b_proj    = (const float*)d_in[5];
    const float* W_router  = (const float*)d_in[6];
    const float* b_router  = (const float*)d_in[7];
    const float* W_experts = (const float*)d_in[8];
    const float* b_experts = (const float*)d_in[9];
    const float* W_head    = (const float*)d_in[10];
    const float* b_head    = (const float*)d_in[11];
    float* out = (float*)d_out;
    float* ws  = (float*)d_ws;

    const size_t need = (size_t)(WT_FLOATS + XP_FLOATS + GATES_FLOATS +
                                 STATS_FLOATS + FLAT_FLOATS);
    const bool use_t = ws_size >= need * sizeof(float);

    size_t off = use_t ? (size_t)WT_FLOATS : 0;
    float* Wt        = ws;
    float* xp_ws     = ws + off;  off += XP_FLOATS;
    float* gates_ws  = ws + off;  off += GATES_FLOATS;
    float* stats_ws  = ws + off;  off += STATS_FLOATS;
    float* flat_part = ws + off;

    k_stats<<<256, 256, 0, stream>>>(x, W_proj, b_proj, W_router, b_router,
                                     W_experts, Wt, xp_ws, gates_ws, stats_ws,
                                     use_t ? 1 : 0);
    if (use_t) {
        k_expert<<<1024, 256, 0, stream>>>(Wt, b_experts, xp_ws, gates_ws, flat_part);
    } else {
        k_expert_direct<<<1024, 256, 0, stream>>>(W_experts, b_experts,
                                                  xp_ws, gates_ws, flat_part);
    }
    k_head<<<NB, 256, 0, stream>>>(flat_part, stats_ws, W_head, b_head, out);
}